// Round 6
// baseline (104.906 us; speedup 1.0000x reference)
//
#include <hip/hip_runtime.h>

#define N_SAMP 16384
#define N_CENT 4096
#define DIM    128
#define LAMBD  1.0f
#define NSLOT  256

typedef _Float16 half8  __attribute__((ext_vector_type(8)));
typedef float    floatx4 __attribute__((ext_vector_type(4)));

// One accumulation slot per 128-B cache line; blocks sharing a slot share
// (bid % 8) so slot lines don't ping-pong across XCDs under round-robin.
struct Slot { float sum; unsigned int cnt; unsigned int pad[30]; };

__device__ __forceinline__ void gload_lds16(const void* g, void* l) {
  __builtin_amdgcn_global_load_lds(
      (__attribute__((address_space(1))) void*)(g),
      (__attribute__((address_space(3))) void*)(l), 16, 0, 0);
}

// ---------------------------------------------------------------------------
// Fused prep (single launch):
//   blocks [0, 1280): quarter-wave (16 lanes) per row.
//     rows [0, N_SAMP): rowk[i] = lambd + sum c*(c-2e) over center y_i
//     rows [N_SAMP, N_SAMP+N_CENT): c2[c] = ||c||^2
//     Block 0 additionally zeroes the 256 accumulation slots.
//   blocks [1280, 2560): f32->f16 convert of E then C, 16B->8B per thread.
// ---------------------------------------------------------------------------
__global__ __launch_bounds__(256) void prep_kernel(
    const float* __restrict__ E, const float* __restrict__ Cc,
    const int* __restrict__ tgt,
    _Float16* __restrict__ Eh, _Float16* __restrict__ Ch,
    float* __restrict__ c2, float* __restrict__ rowk,
    Slot* __restrict__ slots) {
  const int tid = threadIdx.x;
  const int STAT_BLOCKS = (N_SAMP + N_CENT) / 16;  // 1280
  if ((int)blockIdx.x < STAT_BLOCKS) {
    if (blockIdx.x == 0) { slots[tid].sum = 0.f; slots[tid].cnt = 0u; }
    const int row   = blockIdx.x * 16 + (tid >> 4);  // 16 rows per block
    const int l16   = tid & 15;
    if (row < N_SAMP) {
      const int yi = tgt[row];
      const float4* e = (const float4*)(E  + (size_t)row * DIM + l16 * 8);
      const float4* c = (const float4*)(Cc + (size_t)yi  * DIM + l16 * 8);
      float4 e0 = e[0], e1 = e[1], c0 = c[0], c1 = c[1];
      float s = c0.x*(c0.x-2.f*e0.x) + c0.y*(c0.y-2.f*e0.y)
              + c0.z*(c0.z-2.f*e0.z) + c0.w*(c0.w-2.f*e0.w)
              + c1.x*(c1.x-2.f*e1.x) + c1.y*(c1.y-2.f*e1.y)
              + c1.z*(c1.z-2.f*e1.z) + c1.w*(c1.w-2.f*e1.w);
      s += __shfl_down(s, 8, 16);
      s += __shfl_down(s, 4, 16);
      s += __shfl_down(s, 2, 16);
      s += __shfl_down(s, 1, 16);
      if (l16 == 0) rowk[row] = LAMBD + s;
    } else {
      const int cI = row - N_SAMP;
      const float4* c = (const float4*)(Cc + (size_t)cI * DIM + l16 * 8);
      float4 c0 = c[0], c1 = c[1];
      float s = c0.x*c0.x + c0.y*c0.y + c0.z*c0.z + c0.w*c0.w
              + c1.x*c1.x + c1.y*c1.y + c1.z*c1.z + c1.w*c1.w;
      s += __shfl_down(s, 8, 16);
      s += __shfl_down(s, 4, 16);
      s += __shfl_down(s, 2, 16);
      s += __shfl_down(s, 1, 16);
      if (l16 == 0) c2[cI] = s;
    }
  } else {
    const int t = ((int)blockIdx.x - STAT_BLOCKS) * 256 + tid;
    const int NE8 = N_SAMP * DIM / 8;   // 262144
    const float4* src;
    half8* dst;
    int idx;
    if (t < NE8) { src = (const float4*)E;  dst = (half8*)Eh; idx = t; }
    else         { src = (const float4*)Cc; dst = (half8*)Ch; idx = t - NE8; }
    float4 a = src[(size_t)idx * 2], b = src[(size_t)idx * 2 + 1];
    half8 h;
    h[0]=(_Float16)a.x; h[1]=(_Float16)a.y; h[2]=(_Float16)a.z; h[3]=(_Float16)a.w;
    h[4]=(_Float16)b.x; h[5]=(_Float16)b.y; h[6]=(_Float16)b.z; h[7]=(_Float16)b.w;
    dst[idx] = h;
  }
}

// ---------------------------------------------------------------------------
// Main GEMM: 128x128 tile, 256 threads (4 waves, 2x2), K=128 one-shot.
// B staged in LDS (32 KB, XOR swizzle -> 0 bank conflicts); A loaded
// global->registers directly (no LDS, no barrier dependency). 3 blocks/CU
// (launch_bounds(256,3)): other blocks' MFMA covers one block's stage drain.
// Fused epilogue + bucketed slot atomics.
// ---------------------------------------------------------------------------
__global__ __launch_bounds__(256, 3) void center_gemm_kernel(
    const _Float16* __restrict__ Eh, const _Float16* __restrict__ Ch,
    const float* __restrict__ c2, const float* __restrict__ rowk,
    const int* __restrict__ tgt,
    Slot* __restrict__ slots) {
  __shared__ _Float16 Bs[128 * DIM];   // 32 KB
  __shared__ float rowkS[128];
  __shared__ float c2S[128];
  __shared__ int   yS[128];
  __shared__ float swsum[4];
  __shared__ int   swcnt[4];

  const int tid  = threadIdx.x;
  const int w    = tid >> 6;           // 0..3
  const int lane = tid & 63;
  const int q = lane >> 4, r = lane & 15;

  // Block mapping (XCD-grouped; neutral but harmless).
  const int bid = blockIdx.x;          // 0..4095
  const int xcd = bid & 7;
  const int j   = bid >> 3;            // 0..511
  const int bm  = xcd * 16 + (j & 15); // 0..127
  const int bn  = j >> 4;              // 0..31

  // ---- stage B tile (32 KB) into LDS with XOR-swizzled source chunks ----
  {
    const char* gB = (const char*)(Ch + (size_t)bn * 128 * DIM);
    char* lB = (char*)Bs;
    const int p  = lane & 15;
    const int r4 = lane >> 4;
    #pragma unroll
    for (int it = 0; it < 8; ++it) {
      const int off = (w * 8 + it) * 1024;
      const int row = (w * 8 + it) * 4 + r4;
      const int gof = row * 256 + (p ^ (row & 15)) * 16;
      gload_lds16(gB + gof, lB + off);
    }
  }

  // ---- A fragments: global -> registers (16 half8 loads per wave) ----
  const int wm = w >> 1, wn = w & 1;
  const int row0 = wm * 64, col0 = wn * 64;
  half8 areg[4][4];   // [ks][mt]
  #pragma unroll
  for (int ks = 0; ks < 4; ++ks)
    #pragma unroll
    for (int mt = 0; mt < 4; ++mt)
      areg[ks][mt] = *(const half8*)&Eh[
          (size_t)(bm * 128 + row0 + mt * 16 + r) * DIM + ks * 32 + q * 8];

  if (tid < 128) {
    rowkS[tid] = rowk[bm * 128 + tid];
    yS[tid]    = tgt[bm * 128 + tid];
    c2S[tid]   = c2[bn * 128 + tid];
  }
  __syncthreads();

  floatx4 acc[4][4];
  #pragma unroll
  for (int a = 0; a < 4; ++a)
    #pragma unroll
    for (int b = 0; b < 4; ++b)
      acc[a][b] = (floatx4){0.f, 0.f, 0.f, 0.f};

  #pragma unroll
  for (int ks = 0; ks < 4; ++ks) {
    const int cidx = ks * 4 + q;
    half8 bf[4];
    #pragma unroll
    for (int nt = 0; nt < 4; ++nt)
      bf[nt] = *(const half8*)&Bs[(col0 + nt * 16 + r) * DIM + ((cidx ^ r) * 8)];
    #pragma unroll
    for (int mt = 0; mt < 4; ++mt)
      #pragma unroll
      for (int nt = 0; nt < 4; ++nt)
        acc[mt][nt] = __builtin_amdgcn_mfma_f32_16x16x32_f16(areg[ks][mt], bf[nt], acc[mt][nt], 0, 0, 0);
  }

  // ---- fused epilogue ----
  float lsum = 0.f;
  int   lcnt = 0;
  #pragma unroll
  for (int mt = 0; mt < 4; ++mt) {
    float rk[4]; int yv[4];
    #pragma unroll
    for (int rg = 0; rg < 4; ++rg) {
      const int row = row0 + mt * 16 + q * 4 + rg;
      rk[rg] = rowkS[row];
      yv[rg] = yS[row];
    }
    #pragma unroll
    for (int nt = 0; nt < 4; ++nt) {
      const int col  = col0 + nt * 16 + r;
      const float c2v = c2S[col];
      const int gcol = bn * 128 + col;
      #pragma unroll
      for (int rg = 0; rg < 4; ++rg) {
        const float v = rk[rg] + 2.f * acc[mt][nt][rg] - c2v;
        const bool mined = (v > 0.f) & (gcol != yv[rg]);
        lsum += mined ? v : 0.f;
        lcnt += mined ? 1 : 0;
      }
    }
  }

  #pragma unroll
  for (int off = 32; off > 0; off >>= 1) {
    lsum += __shfl_down(lsum, off);
    lcnt += __shfl_down(lcnt, off);
  }
  if (lane == 0) { swsum[w] = lsum; swcnt[w] = lcnt; }
  __syncthreads();
  if (tid == 0) {
    const float s = swsum[0] + swsum[1] + swsum[2] + swsum[3];
    const int   c = swcnt[0] + swcnt[1] + swcnt[2] + swcnt[3];
    Slot* sl = &slots[bid & (NSLOT - 1)];
    atomicAdd(&sl->sum, s);
    atomicAdd(&sl->cnt, (unsigned int)c);
  }
}

__global__ __launch_bounds__(256) void finalize_kernel(
    const Slot* __restrict__ slots, float* __restrict__ out) {
  const int tid = threadIdx.x;
  float s = slots[tid].sum;
  unsigned int c = slots[tid].cnt;
  #pragma unroll
  for (int off = 32; off > 0; off >>= 1) {
    s += __shfl_down(s, off);
    c += __shfl_down(c, off);
  }
  __shared__ float ss[4];
  __shared__ unsigned int sc[4];
  if ((tid & 63) == 0) { ss[tid >> 6] = s; sc[tid >> 6] = c; }
  __syncthreads();
  if (tid == 0) {
    const float S = ss[0] + ss[1] + ss[2] + ss[3];
    const unsigned int C = sc[0] + sc[1] + sc[2] + sc[3];
    out[0] = (C > 0u) ? (S / (float)C) : 0.f;
  }
}

// ---------------------------------------------------------------------------
// Fallback (tiny ws): fp32 vector path, one block per sample.
// ---------------------------------------------------------------------------
__global__ void zero_kernel(float* ws_sum, unsigned int* ws_cnt) {
  if (threadIdx.x == 0) { *ws_sum = 0.f; *ws_cnt = 0u; }
}

__global__ void finalize_simple(const float* __restrict__ ws_sum,
                                const unsigned int* __restrict__ ws_cnt,
                                float* __restrict__ out) {
  if (threadIdx.x == 0 && blockIdx.x == 0) {
    const unsigned int c = *ws_cnt;
    out[0] = (c > 0u) ? (*ws_sum / (float)c) : 0.f;
  }
}

__global__ __launch_bounds__(256) void fallback_kernel(
    const float* __restrict__ E, const float* __restrict__ Cc,
    const int* __restrict__ tgt,
    float* __restrict__ ws_sum, unsigned int* __restrict__ ws_cnt) {
  __shared__ float eS[DIM];
  __shared__ float apS;
  const int i = blockIdx.x;
  const int tid = threadIdx.x;
  if (tid < DIM) eS[tid] = E[(size_t)i * DIM + tid];
  __syncthreads();
  const int yi = tgt[i];
  float dloc[16];
  #pragma unroll
  for (int j = 0; j < 16; ++j) {
    const int c = tid + 256 * j;
    const float* cp = Cc + (size_t)c * DIM;
    float s = 0.f;
    for (int d = 0; d < DIM; d += 4) {
      float4 cv = *(const float4*)(cp + d);
      s += cv.x * (cv.x - 2.f * eS[d + 0]) + cv.y * (cv.y - 2.f * eS[d + 1])
         + cv.z * (cv.z - 2.f * eS[d + 2]) + cv.w * (cv.w - 2.f * eS[d + 3]);
    }
    dloc[j] = s;
    if (c == yi) apS = s;
  }
  __syncthreads();
  const float apv = apS;
  float lsum = 0.f; int lcnt = 0;
  #pragma unroll
  for (int j = 0; j < 16; ++j) {
    const int c = tid + 256 * j;
    const float v = LAMBD + apv - dloc[j];
    const bool mined = (v > 0.f) & (c != yi);
    lsum += mined ? v : 0.f;
    lcnt += mined ? 1 : 0;
  }
  #pragma unroll
  for (int off = 32; off > 0; off >>= 1) {
    lsum += __shfl_down(lsum, off);
    lcnt += __shfl_down(lcnt, off);
  }
  __shared__ float swsum[4];
  __shared__ int   swcnt[4];
  const int w = tid >> 6, lane = tid & 63;
  if (lane == 0) { swsum[w] = lsum; swcnt[w] = lcnt; }
  __syncthreads();
  if (tid == 0) {
    atomicAdd(ws_sum, swsum[0] + swsum[1] + swsum[2] + swsum[3]);
    atomicAdd(ws_cnt, (unsigned int)(swcnt[0] + swcnt[1] + swcnt[2] + swcnt[3]));
  }
}

extern "C" void kernel_launch(void* const* d_in, const int* in_sizes, int n_in,
                              void* d_out, int out_size, void* d_ws, size_t ws_size,
                              hipStream_t stream) {
  const float* E   = (const float*)d_in[0];
  const int*   tgt = (const int*)d_in[1];
  const float* Cc  = (const float*)d_in[2];
  float* out = (float*)d_out;

  const size_t EH_BYTES = (size_t)N_SAMP * DIM * 2;   // 4 MB
  const size_t CH_BYTES = (size_t)N_CENT * DIM * 2;   // 1 MB
  const size_t C2_BYTES = (size_t)N_CENT * 4;         // 16 KB
  const size_t RK_BYTES = (size_t)N_SAMP * 4;         // 64 KB
  const size_t SL_BYTES = (size_t)NSLOT * sizeof(Slot); // 32 KB
  const size_t NEEDED = EH_BYTES + CH_BYTES + C2_BYTES + RK_BYTES + SL_BYTES;

  char* ws = (char*)d_ws;
  if (ws_size >= NEEDED) {
    _Float16* Eh = (_Float16*)ws;
    _Float16* Ch = (_Float16*)(ws + EH_BYTES);
    float* c2    = (float*)(ws + EH_BYTES + CH_BYTES);
    float* rowk  = (float*)(ws + EH_BYTES + CH_BYTES + C2_BYTES);
    Slot* slots  = (Slot*)(ws + EH_BYTES + CH_BYTES + C2_BYTES + RK_BYTES);

    const int STAT_BLOCKS = (N_SAMP + N_CENT) / 16;                       // 1280
    const int CONV_BLOCKS = (N_SAMP * DIM / 8 + N_CENT * DIM / 8) / 256;  // 1280
    prep_kernel<<<STAT_BLOCKS + CONV_BLOCKS, 256, 0, stream>>>(
        E, Cc, tgt, Eh, Ch, c2, rowk, slots);
    center_gemm_kernel<<<(N_CENT / 128) * (N_SAMP / 128), 256, 0, stream>>>(
        Eh, Ch, c2, rowk, tgt, slots);
    finalize_kernel<<<1, 256, 0, stream>>>(slots, out);
  } else {
    float* ws_sum = (float*)ws;
    unsigned int* ws_cnt = (unsigned int*)(ws_sum + 1);
    zero_kernel<<<1, 64, 0, stream>>>(ws_sum, ws_cnt);
    fallback_kernel<<<N_SAMP, 256, 0, stream>>>(E, Cc, tgt, ws_sum, ws_cnt);
    finalize_simple<<<1, 64, 0, stream>>>(ws_sum, ws_cnt, out);
  }
}